// Round 2
// baseline (1858.707 us; speedup 1.0000x reference)
//
#include <hip/hip_runtime.h>

#define N_NODES 100000
#define N_EDGES 1600000
#define FEAT 256
#define BM 64
#define BN 64
#define BK 64
#define LDSS 68   // LDS row stride (floats), 16B-aligned, breaks pow2 conflicts

// MODE 0: C = (A @ B) * norm            (B = weight, [K][O] row-major)
// MODE 1: C = relu(agg*norm + bias + A @ B^T + res_b)   (B = res_w, [O][K] row-major)
template<int MODE>
__global__ __launch_bounds__(256) void gemm_kernel(
    const float* __restrict__ A,
    const float* __restrict__ B,
    const float* __restrict__ norm,
    const float* __restrict__ bias,
    const float* __restrict__ res_b,
    const float* __restrict__ agg,
    float* __restrict__ C)
{
    __shared__ float A_T[BK][LDSS];   // A_T[k][m]
    __shared__ float B_s[BK][LDSS];   // B_s[k][n]

    const int t  = threadIdx.x;
    const int m0 = blockIdx.x * BM;
    const int n0 = blockIdx.y * BN;
    const int tx = t & 15;            // 16 threads across N
    const int ty = t >> 4;            // 16 threads across M

    float acc[4][4] = {};

    for (int k0 = 0; k0 < FEAT; k0 += BK) {
        // ---- stage A (transposed): A_T[k][m] = A[(m0+m)*FEAT + k0+k]
        #pragma unroll
        for (int i = 0; i < 4; ++i) {
            int idx = i * 256 + t;          // 0..1023
            int m   = idx >> 4;             // 0..63
            int k4  = (idx & 15) * 4;       // 0..60
            int row = m0 + m;
            float4 v = make_float4(0.f, 0.f, 0.f, 0.f);
            if (row < N_NODES)
                v = *(const float4*)&A[(size_t)row * FEAT + k0 + k4];
            A_T[k4 + 0][m] = v.x;
            A_T[k4 + 1][m] = v.y;
            A_T[k4 + 2][m] = v.z;
            A_T[k4 + 3][m] = v.w;
        }
        // ---- stage B
        #pragma unroll
        for (int i = 0; i < 4; ++i) {
            int idx = i * 256 + t;
            if (MODE == 0) {
                int k  = idx >> 4;
                int n4 = (idx & 15) * 4;
                float4 v = *(const float4*)&B[(size_t)(k0 + k) * FEAT + n0 + n4];
                *(float4*)&B_s[k][n4] = v;
            } else {
                int n  = idx >> 4;
                int k4 = (idx & 15) * 4;
                float4 v = *(const float4*)&B[(size_t)(n0 + n) * FEAT + k0 + k4];
                B_s[k4 + 0][n] = v.x;
                B_s[k4 + 1][n] = v.y;
                B_s[k4 + 2][n] = v.z;
                B_s[k4 + 3][n] = v.w;
            }
        }
        __syncthreads();

        // ---- compute 4x4 per thread
        #pragma unroll
        for (int kk = 0; kk < BK; ++kk) {
            float4 av = *(const float4*)&A_T[kk][ty * 4];
            float4 bv = *(const float4*)&B_s[kk][tx * 4];
            const float a[4] = {av.x, av.y, av.z, av.w};
            const float b[4] = {bv.x, bv.y, bv.z, bv.w};
            #pragma unroll
            for (int i = 0; i < 4; ++i)
                #pragma unroll
                for (int j = 0; j < 4; ++j)
                    acc[i][j] = fmaf(a[i], b[j], acc[i][j]);
        }
        __syncthreads();
    }

    // ---- epilogue
    if (MODE == 0) {
        #pragma unroll
        for (int i = 0; i < 4; ++i) {
            int row = m0 + ty * 4 + i;
            if (row < N_NODES) {
                float nm = norm[row];
                float4 o;
                o.x = acc[i][0] * nm;
                o.y = acc[i][1] * nm;
                o.z = acc[i][2] * nm;
                o.w = acc[i][3] * nm;
                *(float4*)&C[(size_t)row * FEAT + n0 + tx * 4] = o;
            }
        }
    } else {
        float4 bv = *(const float4*)&bias[n0 + tx * 4];
        float4 rb = *(const float4*)&res_b[n0 + tx * 4];
        #pragma unroll
        for (int i = 0; i < 4; ++i) {
            int row = m0 + ty * 4 + i;
            if (row < N_NODES) {
                float nm = norm[row];
                float4 ag = *(const float4*)&agg[(size_t)row * FEAT + n0 + tx * 4];
                float4 o;
                o.x = fmaxf(fmaf(ag.x, nm, bv.x) + acc[i][0] + rb.x, 0.f);
                o.y = fmaxf(fmaf(ag.y, nm, bv.y) + acc[i][1] + rb.y, 0.f);
                o.z = fmaxf(fmaf(ag.z, nm, bv.z) + acc[i][2] + rb.z, 0.f);
                o.w = fmaxf(fmaf(ag.w, nm, bv.w) + acc[i][3] + rb.w, 0.f);
                *(float4*)&C[(size_t)row * FEAT + n0 + tx * 4] = o;
            }
        }
    }
}

// scatter: for each edge e, agg[dst[e]][:] += hw[src[e]][:]
__global__ __launch_bounds__(256) void scatter_kernel(
    const float* __restrict__ hw,
    const int*   __restrict__ src,
    const int*   __restrict__ dst,
    float*       __restrict__ agg)
{
    const int t  = threadIdx.x;          // feature index 0..255
    const int e0 = blockIdx.x * 8;
    #pragma unroll
    for (int i = 0; i < 8; ++i) {
        int e = e0 + i;
        if (e < N_EDGES) {
            int s = src[e];
            int d = dst[e];
            atomicAdd(&agg[(size_t)d * FEAT + t], hw[(size_t)s * FEAT + t]);
        }
    }
}

extern "C" void kernel_launch(void* const* d_in, const int* in_sizes, int n_in,
                              void* d_out, int out_size, void* d_ws, size_t ws_size,
                              hipStream_t stream) {
    const float* h      = (const float*)d_in[0];
    const float* norm   = (const float*)d_in[1];
    const int*   src    = (const int*)d_in[2];
    const int*   dst    = (const int*)d_in[3];
    const float* weight = (const float*)d_in[4];
    const float* bias   = (const float*)d_in[5];
    const float* res_w  = (const float*)d_in[6];
    const float* res_b  = (const float*)d_in[7];
    float* out = (float*)d_out;
    float* hw  = (float*)d_ws;   // [N_NODES][FEAT] fp32 = 102.4 MB

    // agg accumulates directly in d_out; zero it (harness poisons with 0xAA)
    hipMemsetAsync(out, 0, (size_t)N_NODES * FEAT * sizeof(float), stream);

    dim3 gdim((N_NODES + BM - 1) / BM, FEAT / BN);
    gemm_kernel<0><<<gdim, 256, 0, stream>>>(h, weight, norm, nullptr, nullptr, nullptr, hw);
    scatter_kernel<<<N_EDGES / 8, 256, 0, stream>>>(hw, src, dst, out);
    gemm_kernel<1><<<gdim, 256, 0, stream>>>(h, res_w, norm, bias, res_b, out, out);
}

// Round 3
// 1215.933 us; speedup vs baseline: 1.5286x; 1.5286x over previous
//
#include <hip/hip_runtime.h>

#define N_NODES 100000
#define N_EDGES 1600000
#define FEAT 256
#define BM 64
#define BN 64
#define BK 64
#define LDSS 68   // LDS row stride (floats), 16B-aligned, breaks pow2 conflicts

// ---------------- workspace layout ----------------
// hw      : [N_NODES][FEAT] fp32                     102,400,000 B
// offs    : [N_NODES+1] int   (CSR row offsets)
// cursor  : [N_NODES]   int   (fill cursors)
// deg     : [N_NODES]   int   (histogram)
// csr_src : [N_EDGES]   int   (src ids grouped by dst)
constexpr size_t OFF_HW     = 0;
constexpr size_t HW_BYTES   = (size_t)N_NODES * FEAT * 4;
constexpr size_t OFF_OFFS   = HW_BYTES;
constexpr size_t OFF_CURSOR = OFF_OFFS   + 400128;
constexpr size_t OFF_DEG    = OFF_CURSOR + 400128;
constexpr size_t OFF_CSR    = OFF_DEG    + 400128;
constexpr size_t WS_NEEDED  = OFF_CSR + (size_t)N_EDGES * 4;

// MODE 0: C = (A @ B) * norm            (B = weight, [K][O] row-major)
// MODE 1: C = relu(agg*norm + bias + A @ B^T + res_b)   (B = res_w, [O][K] row-major)
template<int MODE>
__global__ __launch_bounds__(256) void gemm_kernel(
    const float* __restrict__ A,
    const float* __restrict__ B,
    const float* __restrict__ norm,
    const float* __restrict__ bias,
    const float* __restrict__ res_b,
    const float* __restrict__ agg,
    float* __restrict__ C)
{
    __shared__ float A_T[BK][LDSS];   // A_T[k][m]
    __shared__ float B_s[BK][LDSS];   // B_s[k][n]

    const int t  = threadIdx.x;
    const int m0 = blockIdx.x * BM;
    const int n0 = blockIdx.y * BN;
    const int tx = t & 15;            // 16 threads across N
    const int ty = t >> 4;            // 16 threads across M

    float acc[4][4] = {};

    for (int k0 = 0; k0 < FEAT; k0 += BK) {
        #pragma unroll
        for (int i = 0; i < 4; ++i) {
            int idx = i * 256 + t;          // 0..1023
            int m   = idx >> 4;             // 0..63
            int k4  = (idx & 15) * 4;       // 0..60
            int row = m0 + m;
            float4 v = make_float4(0.f, 0.f, 0.f, 0.f);
            if (row < N_NODES)
                v = *(const float4*)&A[(size_t)row * FEAT + k0 + k4];
            A_T[k4 + 0][m] = v.x;
            A_T[k4 + 1][m] = v.y;
            A_T[k4 + 2][m] = v.z;
            A_T[k4 + 3][m] = v.w;
        }
        #pragma unroll
        for (int i = 0; i < 4; ++i) {
            int idx = i * 256 + t;
            if (MODE == 0) {
                int k  = idx >> 4;
                int n4 = (idx & 15) * 4;
                float4 v = *(const float4*)&B[(size_t)(k0 + k) * FEAT + n0 + n4];
                *(float4*)&B_s[k][n4] = v;
            } else {
                int n  = idx >> 4;
                int k4 = (idx & 15) * 4;
                float4 v = *(const float4*)&B[(size_t)(n0 + n) * FEAT + k0 + k4];
                B_s[k4 + 0][n] = v.x;
                B_s[k4 + 1][n] = v.y;
                B_s[k4 + 2][n] = v.z;
                B_s[k4 + 3][n] = v.w;
            }
        }
        __syncthreads();

        #pragma unroll
        for (int kk = 0; kk < BK; ++kk) {
            float4 av = *(const float4*)&A_T[kk][ty * 4];
            float4 bv = *(const float4*)&B_s[kk][tx * 4];
            const float a[4] = {av.x, av.y, av.z, av.w};
            const float b[4] = {bv.x, bv.y, bv.z, bv.w};
            #pragma unroll
            for (int i = 0; i < 4; ++i)
                #pragma unroll
                for (int j = 0; j < 4; ++j)
                    acc[i][j] = fmaf(a[i], b[j], acc[i][j]);
        }
        __syncthreads();
    }

    if (MODE == 0) {
        #pragma unroll
        for (int i = 0; i < 4; ++i) {
            int row = m0 + ty * 4 + i;
            if (row < N_NODES) {
                float nm = norm[row];
                float4 o;
                o.x = acc[i][0] * nm;
                o.y = acc[i][1] * nm;
                o.z = acc[i][2] * nm;
                o.w = acc[i][3] * nm;
                *(float4*)&C[(size_t)row * FEAT + n0 + tx * 4] = o;
            }
        }
    } else {
        float4 bv = *(const float4*)&bias[n0 + tx * 4];
        float4 rb = *(const float4*)&res_b[n0 + tx * 4];
        #pragma unroll
        for (int i = 0; i < 4; ++i) {
            int row = m0 + ty * 4 + i;
            if (row < N_NODES) {
                float nm = norm[row];
                float4 ag = *(const float4*)&agg[(size_t)row * FEAT + n0 + tx * 4];
                float4 o;
                o.x = fmaxf(fmaf(ag.x, nm, bv.x) + acc[i][0] + rb.x, 0.f);
                o.y = fmaxf(fmaf(ag.y, nm, bv.y) + acc[i][1] + rb.y, 0.f);
                o.z = fmaxf(fmaf(ag.z, nm, bv.z) + acc[i][2] + rb.z, 0.f);
                o.w = fmaxf(fmaf(ag.w, nm, bv.w) + acc[i][3] + rb.w, 0.f);
                *(float4*)&C[(size_t)row * FEAT + n0 + tx * 4] = o;
            }
        }
    }
}

// -------- CSR build --------
__global__ __launch_bounds__(256) void hist_kernel(
    const int* __restrict__ dst, int* __restrict__ deg)
{
    int e = blockIdx.x * 256 + threadIdx.x;
    if (e < N_EDGES) atomicAdd(&deg[dst[e]], 1);
}

#define SCAN_THREADS 1024
__global__ __launch_bounds__(SCAN_THREADS) void scan_kernel(
    const int* __restrict__ deg, int* __restrict__ offs, int* __restrict__ cursor)
{
    __shared__ int part[SCAN_THREADS];
    const int t = threadIdx.x;
    const int CHUNK = (N_NODES + SCAN_THREADS - 1) / SCAN_THREADS;  // 98
    const int lo = t * CHUNK;
    const int hi = min(lo + CHUNK, N_NODES);
    int s = 0;
    for (int i = lo; i < hi; ++i) s += deg[i];
    part[t] = s;
    __syncthreads();
    for (int d = 1; d < SCAN_THREADS; d <<= 1) {   // inclusive Hillis-Steele
        int v = (t >= d) ? part[t - d] : 0;
        __syncthreads();
        part[t] += v;
        __syncthreads();
    }
    int prefix = (t == 0) ? 0 : part[t - 1];       // exclusive
    for (int i = lo; i < hi; ++i) {
        offs[i] = prefix;
        cursor[i] = prefix;
        prefix += deg[i];
    }
    if (t == SCAN_THREADS - 1) offs[N_NODES] = prefix;
}

__global__ __launch_bounds__(256) void fill_kernel(
    const int* __restrict__ src, const int* __restrict__ dst,
    int* __restrict__ cursor, int* __restrict__ csr_src)
{
    int e = blockIdx.x * 256 + threadIdx.x;
    if (e < N_EDGES) {
        int d = dst[e];
        int p = atomicAdd(&cursor[d], 1);
        csr_src[p] = src[e];
    }
}

// -------- gather-aggregate: one wave per node, lane = 4 features --------
__global__ __launch_bounds__(256) void aggregate_kernel(
    const float* __restrict__ hw,
    const int*   __restrict__ offs,
    const int*   __restrict__ csr_src,
    float*       __restrict__ agg)
{
    const int wave = threadIdx.x >> 6;
    const int lane = threadIdx.x & 63;
    const int n    = blockIdx.x * 4 + wave;
    if (n >= N_NODES) return;
    const int start = offs[n];
    const int end   = offs[n + 1];
    float4 a0 = make_float4(0.f, 0.f, 0.f, 0.f);
    float4 a1 = make_float4(0.f, 0.f, 0.f, 0.f);
    int e = start;
    for (; e + 1 < end; e += 2) {
        int s0 = csr_src[e];
        int s1 = csr_src[e + 1];
        float4 v0 = *(const float4*)&hw[(size_t)s0 * FEAT + lane * 4];
        float4 v1 = *(const float4*)&hw[(size_t)s1 * FEAT + lane * 4];
        a0.x += v0.x; a0.y += v0.y; a0.z += v0.z; a0.w += v0.w;
        a1.x += v1.x; a1.y += v1.y; a1.z += v1.z; a1.w += v1.w;
    }
    if (e < end) {
        int s0 = csr_src[e];
        float4 v0 = *(const float4*)&hw[(size_t)s0 * FEAT + lane * 4];
        a0.x += v0.x; a0.y += v0.y; a0.z += v0.z; a0.w += v0.w;
    }
    float4 o;
    o.x = a0.x + a1.x; o.y = a0.y + a1.y; o.z = a0.z + a1.z; o.w = a0.w + a1.w;
    *(float4*)&agg[(size_t)n * FEAT + lane * 4] = o;
}

// -------- fallback atomic scatter (only if ws too small) --------
__global__ __launch_bounds__(256) void scatter_kernel(
    const float* __restrict__ hw,
    const int*   __restrict__ src,
    const int*   __restrict__ dst,
    float*       __restrict__ agg)
{
    const int t  = threadIdx.x;
    const int e0 = blockIdx.x * 8;
    #pragma unroll
    for (int i = 0; i < 8; ++i) {
        int e = e0 + i;
        if (e < N_EDGES) {
            int s = src[e];
            int d = dst[e];
            atomicAdd(&agg[(size_t)d * FEAT + t], hw[(size_t)s * FEAT + t]);
        }
    }
}

extern "C" void kernel_launch(void* const* d_in, const int* in_sizes, int n_in,
                              void* d_out, int out_size, void* d_ws, size_t ws_size,
                              hipStream_t stream) {
    const float* h      = (const float*)d_in[0];
    const float* norm   = (const float*)d_in[1];
    const int*   src    = (const int*)d_in[2];
    const int*   dst    = (const int*)d_in[3];
    const float* weight = (const float*)d_in[4];
    const float* bias   = (const float*)d_in[5];
    const float* res_w  = (const float*)d_in[6];
    const float* res_b  = (const float*)d_in[7];
    float* out = (float*)d_out;

    char* ws      = (char*)d_ws;
    float* hw     = (float*)(ws + OFF_HW);
    int*   offs   = (int*)(ws + OFF_OFFS);
    int*   cursor = (int*)(ws + OFF_CURSOR);
    int*   deg    = (int*)(ws + OFF_DEG);
    int*   csr    = (int*)(ws + OFF_CSR);

    dim3 gdim((N_NODES + BM - 1) / BM, FEAT / BN);

    // hw = (h @ W) * norm
    gemm_kernel<0><<<gdim, 256, 0, stream>>>(h, weight, norm, nullptr, nullptr, nullptr, hw);

    if (ws_size >= WS_NEEDED) {
        // CSR build + gather aggregation (no fp32 atomics)
        hipMemsetAsync(deg, 0, (size_t)N_NODES * 4, stream);
        hist_kernel<<<(N_EDGES + 255) / 256, 256, 0, stream>>>(dst, deg);
        scan_kernel<<<1, SCAN_THREADS, 0, stream>>>(deg, offs, cursor);
        fill_kernel<<<(N_EDGES + 255) / 256, 256, 0, stream>>>(src, dst, cursor, csr);
        aggregate_kernel<<<(N_NODES + 3) / 4, 256, 0, stream>>>(hw, offs, csr, out);
    } else {
        hipMemsetAsync(out, 0, (size_t)N_NODES * FEAT * sizeof(float), stream);
        scatter_kernel<<<N_EDGES / 8, 256, 0, stream>>>(hw, src, dst, out);
    }

    // out = relu(agg*norm + bias + h @ res_w^T + res_b)
    gemm_kernel<1><<<gdim, 256, 0, stream>>>(h, res_w, norm, bias, res_b, out, out);
}

// Round 4
// 796.662 us; speedup vs baseline: 2.3331x; 1.5263x over previous
//
#include <hip/hip_runtime.h>

#define N_NODES 100000
#define N_EDGES 1600000
#define FEAT 256
#define KTOT 512

typedef __attribute__((ext_vector_type(8))) short short8v;     // 8 bf16 = 4 VGPRs
typedef __attribute__((ext_vector_type(4))) float f32x4;
typedef __attribute__((ext_vector_type(4))) unsigned short ushort4v;

__device__ __forceinline__ unsigned short f2bf(float f) {
    unsigned u = __float_as_uint(f);
    return (unsigned short)((u + 0x7FFFu + ((u >> 16) & 1u)) >> 16);   // RNE
}
__device__ __forceinline__ float bf2f(unsigned short s) {
    return __uint_as_float(((unsigned)s) << 16);
}
__device__ __forceinline__ short8v zero8() {
    short8v v;
    #pragma unroll
    for (int i = 0; i < 8; ++i) v[i] = 0;
    return v;
}

// ---------------- workspace layout ----------------
// xh  : [N][512] bf16  — cols 0:256 = z (aggregated), 256:512 = bf16(h)
// Bt  : [256][512] bf16 — Bt[n][k<256]=W[k][n], Bt[n][k>=256]=res_w[n][k-256]
constexpr size_t OFF_XH     = 0;
constexpr size_t XH_BYTES   = (size_t)N_NODES * KTOT * 2;      // 102,400,000
constexpr size_t OFF_BT     = XH_BYTES;
constexpr size_t OFF_OFFS   = OFF_BT + 262144;
constexpr size_t OFF_CURSOR = OFF_OFFS + 400128;
constexpr size_t OFF_DEG    = OFF_CURSOR + 400128;
constexpr size_t OFF_CSR    = OFF_DEG + 400128;
constexpr size_t WS_NEEDED  = OFF_CSR + (size_t)N_EDGES * 4;   // ~110.3 MB

// ---------------- prep kernels ----------------
__global__ __launch_bounds__(256) void cast_h_kernel(
    const float* __restrict__ h, unsigned short* __restrict__ xh)
{
    int tid = blockIdx.x * 256 + threadIdx.x;      // 3.2M threads, 8 elems each
    int row = tid >> 5;                            // 32 threads per row
    int c8  = (tid & 31) * 8;
    const float4* p = (const float4*)&h[(size_t)row * FEAT + c8];
    float4 a = p[0], b = p[1];
    unsigned short tmp[8];
    tmp[0]=f2bf(a.x); tmp[1]=f2bf(a.y); tmp[2]=f2bf(a.z); tmp[3]=f2bf(a.w);
    tmp[4]=f2bf(b.x); tmp[5]=f2bf(b.y); tmp[6]=f2bf(b.z); tmp[7]=f2bf(b.w);
    *(short8v*)&xh[(size_t)row * KTOT + 256 + c8] = *(short8v*)tmp;
}

__global__ __launch_bounds__(256) void prep_b_kernel(
    const float* __restrict__ W, const float* __restrict__ res_w,
    unsigned short* __restrict__ Bt)
{
    int n = blockIdx.x, t = threadIdx.x;
    Bt[(size_t)n * KTOT + t]       = f2bf(W[(size_t)t * FEAT + n]);       // W^T
    Bt[(size_t)n * KTOT + 256 + t] = f2bf(res_w[(size_t)n * FEAT + t]);   // res_w
}

// ---------------- CSR build ----------------
__global__ __launch_bounds__(256) void hist_kernel(
    const int* __restrict__ dst, int* __restrict__ deg)
{
    int e = blockIdx.x * 256 + threadIdx.x;
    if (e < N_EDGES) atomicAdd(&deg[dst[e]], 1);
}

#define SCAN_THREADS 1024
__global__ __launch_bounds__(SCAN_THREADS) void scan_kernel(
    const int* __restrict__ deg, int* __restrict__ offs, int* __restrict__ cursor)
{
    __shared__ int part[SCAN_THREADS];
    const int t = threadIdx.x;
    const int CHUNK = (N_NODES + SCAN_THREADS - 1) / SCAN_THREADS;  // 98
    const int lo = t * CHUNK;
    const int hi = min(lo + CHUNK, N_NODES);
    int s = 0;
    for (int i = lo; i < hi; ++i) s += deg[i];
    part[t] = s;
    __syncthreads();
    for (int d = 1; d < SCAN_THREADS; d <<= 1) {
        int v = (t >= d) ? part[t - d] : 0;
        __syncthreads();
        part[t] += v;
        __syncthreads();
    }
    int prefix = (t == 0) ? 0 : part[t - 1];
    for (int i = lo; i < hi; ++i) {
        offs[i] = prefix;
        cursor[i] = prefix;
        prefix += deg[i];
    }
    if (t == SCAN_THREADS - 1) offs[N_NODES] = prefix;
}

__global__ __launch_bounds__(256) void fill_kernel(
    const int* __restrict__ src, const int* __restrict__ dst,
    int* __restrict__ cursor, int* __restrict__ csr_src)
{
    int e = blockIdx.x * 256 + threadIdx.x;
    if (e < N_EDGES) {
        int d = dst[e];
        int p = atomicAdd(&cursor[d], 1);
        csr_src[p] = src[e];
    }
}

// ---------------- aggregate: z[n] = norm[n] * sum_e bf16(h)[src_e]*norm[src_e] ----------------
__global__ __launch_bounds__(256) void aggregate_kernel(
    const float* __restrict__ norm,
    const int*   __restrict__ offs,
    const int*   __restrict__ csr_src,
    unsigned short* __restrict__ xh)     // reads h half (+256), writes z half
{
    const int wave = threadIdx.x >> 6;
    const int lane = threadIdx.x & 63;
    const int n    = blockIdx.x * 4 + wave;
    if (n >= N_NODES) return;
    const int start = offs[n];
    const int end   = offs[n + 1];
    float a0=0,a1=0,a2=0,a3=0, b0=0,b1=0,b2=0,b3=0;
    int e = start;
    for (; e + 1 < end; e += 2) {
        int s0 = csr_src[e];
        int s1 = csr_src[e + 1];
        float m0 = norm[s0], m1 = norm[s1];
        ushort4v v0 = *(const ushort4v*)&xh[(size_t)s0 * KTOT + 256 + lane * 4];
        ushort4v v1 = *(const ushort4v*)&xh[(size_t)s1 * KTOT + 256 + lane * 4];
        a0 = fmaf(bf2f(v0.x), m0, a0); a1 = fmaf(bf2f(v0.y), m0, a1);
        a2 = fmaf(bf2f(v0.z), m0, a2); a3 = fmaf(bf2f(v0.w), m0, a3);
        b0 = fmaf(bf2f(v1.x), m1, b0); b1 = fmaf(bf2f(v1.y), m1, b1);
        b2 = fmaf(bf2f(v1.z), m1, b2); b3 = fmaf(bf2f(v1.w), m1, b3);
    }
    if (e < end) {
        int s0 = csr_src[e];
        float m0 = norm[s0];
        ushort4v v0 = *(const ushort4v*)&xh[(size_t)s0 * KTOT + 256 + lane * 4];
        a0 = fmaf(bf2f(v0.x), m0, a0); a1 = fmaf(bf2f(v0.y), m0, a1);
        a2 = fmaf(bf2f(v0.z), m0, a2); a3 = fmaf(bf2f(v0.w), m0, a3);
    }
    float nm = norm[n];
    unsigned short tmp[4];
    tmp[0] = f2bf((a0 + b0) * nm);
    tmp[1] = f2bf((a1 + b1) * nm);
    tmp[2] = f2bf((a2 + b2) * nm);
    tmp[3] = f2bf((a3 + b3) * nm);
    *(ushort4v*)&xh[(size_t)n * KTOT + lane * 4] = *(ushort4v*)tmp;
}

// ---------------- fused MFMA GEMM: out = relu(xh @ Bt^T + bias + res_b) ----------------
// block tile 128x128, 4 waves in 2x2, wave tile 64x64 (4x4 frags of 16x16x32)
#define GBM 128
#define GBN 128
#define GBK 32
#define LDT 40   // shorts per LDS row = 80 B (16B-aligned, spreads banks)

__global__ __launch_bounds__(256) void mfma_gemm_kernel(
    const unsigned short* __restrict__ xh,   // A: [N][512] bf16
    const unsigned short* __restrict__ Bt,   // [256][512] bf16 (n-major)
    const float* __restrict__ bias,
    const float* __restrict__ res_b,
    float* __restrict__ out)
{
    __shared__ unsigned short As[GBM * LDT];
    __shared__ unsigned short Bs[GBN * LDT];
    const int t    = threadIdx.x;
    const int m0   = blockIdx.x * GBM;
    const int n0   = blockIdx.y * GBN;
    const int wave = t >> 6, lane = t & 63;
    const int wm   = wave >> 1, wn = wave & 1;
    const int lrow = lane & 15, kg = lane >> 4;   // frag row/col + k-group

    f32x4 zf = {0.f, 0.f, 0.f, 0.f};
    f32x4 acc[4][4];
    #pragma unroll
    for (int i = 0; i < 4; ++i)
        #pragma unroll
        for (int j = 0; j < 4; ++j) acc[i][j] = zf;

    for (int k0 = 0; k0 < KTOT; k0 += GBK) {
        #pragma unroll
        for (int it = 0; it < 2; ++it) {
            int idx = it * 256 + t;      // 0..511 -> 128 rows x 4 chunks(16B)
            int row = idx >> 2;
            int ch  = (idx & 3) * 8;     // shorts
            int grow = m0 + row;
            short8v va = zero8();
            if (grow < N_NODES)
                va = *(const short8v*)&xh[(size_t)grow * KTOT + k0 + ch];
            *(short8v*)&As[row * LDT + ch] = va;
            short8v vb = *(const short8v*)&Bt[(size_t)(n0 + row) * KTOT + k0 + ch];
            *(short8v*)&Bs[row * LDT + ch] = vb;
        }
        __syncthreads();

        short8v af[4], bfr[4];
        #pragma unroll
        for (int i = 0; i < 4; ++i) {
            af[i]  = *(const short8v*)&As[(wm * 64 + i * 16 + lrow) * LDT + kg * 8];
            bfr[i] = *(const short8v*)&Bs[(wn * 64 + i * 16 + lrow) * LDT + kg * 8];
        }
        #pragma unroll
        for (int i = 0; i < 4; ++i)
            #pragma unroll
            for (int j = 0; j < 4; ++j)
                acc[i][j] = __builtin_amdgcn_mfma_f32_16x16x32_bf16(
                    af[i], bfr[j], acc[i][j], 0, 0, 0);
        __syncthreads();
    }

    // D layout: col = lane&15, row = 4*(lane>>4) + reg
    #pragma unroll
    for (int j = 0; j < 4; ++j) {
        int col = n0 + wn * 64 + j * 16 + lrow;
        float bb = bias[col] + res_b[col];
        #pragma unroll
        for (int i = 0; i < 4; ++i) {
            int rbase = m0 + wm * 64 + i * 16 + kg * 4;
            #pragma unroll
            for (int r = 0; r < 4; ++r) {
                int row = rbase + r;
                if (row < N_NODES)
                    out[(size_t)row * FEAT + col] = fmaxf(acc[i][j][r] + bb, 0.f);
            }
        }
    }
}

// ================= fallback fp32 path (only if ws too small) =================
#define BM 64
#define BN 64
#define BK 64
#define LDSS 68

template<int MODE>
__global__ __launch_bounds__(256) void gemm_kernel(
    const float* __restrict__ A, const float* __restrict__ B,
    const float* __restrict__ norm, const float* __restrict__ bias,
    const float* __restrict__ res_b, const float* __restrict__ agg,
    float* __restrict__ C)
{
    __shared__ float A_T[BK][LDSS];
    __shared__ float B_s[BK][LDSS];
    const int t = threadIdx.x;
    const int m0 = blockIdx.x * BM, n0 = blockIdx.y * BN;
    const int tx = t & 15, ty = t >> 4;
    float acc[4][4] = {};
    for (int k0 = 0; k0 < FEAT; k0 += BK) {
        #pragma unroll
        for (int i = 0; i < 4; ++i) {
            int idx = i * 256 + t;
            int m = idx >> 4, k4 = (idx & 15) * 4;
            int row = m0 + m;
            float4 v = make_float4(0.f,0.f,0.f,0.f);
            if (row < N_NODES) v = *(const float4*)&A[(size_t)row * FEAT + k0 + k4];
            A_T[k4+0][m]=v.x; A_T[k4+1][m]=v.y; A_T[k4+2][m]=v.z; A_T[k4+3][m]=v.w;
        }
        #pragma unroll
        for (int i = 0; i < 4; ++i) {
            int idx = i * 256 + t;
            if (MODE == 0) {
                int k = idx >> 4, n4 = (idx & 15) * 4;
                *(float4*)&B_s[k][n4] = *(const float4*)&B[(size_t)(k0+k)*FEAT + n0 + n4];
            } else {
                int n = idx >> 4, k4 = (idx & 15) * 4;
                float4 v = *(const float4*)&B[(size_t)(n0+n)*FEAT + k0 + k4];
                B_s[k4+0][n]=v.x; B_s[k4+1][n]=v.y; B_s[k4+2][n]=v.z; B_s[k4+3][n]=v.w;
            }
        }
        __syncthreads();
        #pragma unroll
        for (int kk = 0; kk < BK; ++kk) {
            float4 av = *(const float4*)&A_T[kk][ty*4];
            float4 bv = *(const float4*)&B_s[kk][tx*4];
            const float a[4]={av.x,av.y,av.z,av.w}, b[4]={bv.x,bv.y,bv.z,bv.w};
            #pragma unroll
            for (int i=0;i<4;++i)
                #pragma unroll
                for (int j=0;j<4;++j) acc[i][j]=fmaf(a[i],b[j],acc[i][j]);
        }
        __syncthreads();
    }
    if (MODE == 0) {
        #pragma unroll
        for (int i=0;i<4;++i) {
            int row=m0+ty*4+i;
            if (row<N_NODES) {
                float nm=norm[row];
                float4 o; o.x=acc[i][0]*nm; o.y=acc[i][1]*nm; o.z=acc[i][2]*nm; o.w=acc[i][3]*nm;
                *(float4*)&C[(size_t)row*FEAT+n0+tx*4]=o;
            }
        }
    } else {
        float4 bv=*(const float4*)&bias[n0+tx*4];
        float4 rb=*(const float4*)&res_b[n0+tx*4];
        #pragma unroll
        for (int i=0;i<4;++i) {
            int row=m0+ty*4+i;
            if (row<N_NODES) {
                float nm=norm[row];
                float4 ag=*(const float4*)&agg[(size_t)row*FEAT+n0+tx*4];
                float4 o;
                o.x=fmaxf(fmaf(ag.x,nm,bv.x)+acc[i][0]+rb.x,0.f);
                o.y=fmaxf(fmaf(ag.y,nm,bv.y)+acc[i][1]+rb.y,0.f);
                o.z=fmaxf(fmaf(ag.z,nm,bv.z)+acc[i][2]+rb.z,0.f);
                o.w=fmaxf(fmaf(ag.w,nm,bv.w)+acc[i][3]+rb.w,0.f);
                *(float4*)&C[(size_t)row*FEAT+n0+tx*4]=o;
            }
        }
    }
}

__global__ __launch_bounds__(256) void scatter_kernel(
    const float* __restrict__ hw, const int* __restrict__ src,
    const int* __restrict__ dst, float* __restrict__ agg)
{
    const int t = threadIdx.x;
    const int e0 = blockIdx.x * 8;
    #pragma unroll
    for (int i = 0; i < 8; ++i) {
        int e = e0 + i;
        if (e < N_EDGES) {
            int s = src[e], d = dst[e];
            atomicAdd(&agg[(size_t)d * FEAT + t], hw[(size_t)s * FEAT + t]);
        }
    }
}

extern "C" void kernel_launch(void* const* d_in, const int* in_sizes, int n_in,
                              void* d_out, int out_size, void* d_ws, size_t ws_size,
                              hipStream_t stream) {
    const float* h      = (const float*)d_in[0];
    const float* norm   = (const float*)d_in[1];
    const int*   src    = (const int*)d_in[2];
    const int*   dst    = (const int*)d_in[3];
    const float* weight = (const float*)d_in[4];
    const float* bias   = (const float*)d_in[5];
    const float* res_w  = (const float*)d_in[6];
    const float* res_b  = (const float*)d_in[7];
    float* out = (float*)d_out;
    char* ws = (char*)d_ws;

    if (ws_size >= WS_NEEDED) {
        unsigned short* xh  = (unsigned short*)(ws + OFF_XH);
        unsigned short* Bt  = (unsigned short*)(ws + OFF_BT);
        int* offs   = (int*)(ws + OFF_OFFS);
        int* cursor = (int*)(ws + OFF_CURSOR);
        int* deg    = (int*)(ws + OFF_DEG);
        int* csr    = (int*)(ws + OFF_CSR);

        cast_h_kernel<<<N_NODES * FEAT / 8 / 256, 256, 0, stream>>>(h, xh);
        prep_b_kernel<<<256, 256, 0, stream>>>(weight, res_w, Bt);
        hipMemsetAsync(deg, 0, (size_t)N_NODES * 4, stream);
        hist_kernel<<<(N_EDGES + 255) / 256, 256, 0, stream>>>(dst, deg);
        scan_kernel<<<1, SCAN_THREADS, 0, stream>>>(deg, offs, cursor);
        fill_kernel<<<(N_EDGES + 255) / 256, 256, 0, stream>>>(src, dst, cursor, csr);
        aggregate_kernel<<<(N_NODES + 3) / 4, 256, 0, stream>>>(norm, offs, csr, xh);
        dim3 gg((N_NODES + GBM - 1) / GBM, FEAT / GBN);
        mfma_gemm_kernel<<<gg, 256, 0, stream>>>(xh, Bt, bias, res_b, out);
    } else {
        float* hw = (float*)ws;
        dim3 gdim((N_NODES + BM - 1) / BM, FEAT / BN);
        gemm_kernel<0><<<gdim, 256, 0, stream>>>(h, weight, norm, nullptr, nullptr, nullptr, hw);
        hipMemsetAsync(out, 0, (size_t)N_NODES * FEAT * sizeof(float), stream);
        scatter_kernel<<<N_EDGES / 8, 256, 0, stream>>>(hw, src, dst, out);
        gemm_kernel<1><<<gdim, 256, 0, stream>>>(h, res_w, norm, bias, res_b, out, out);
    }
}

// Round 6
// 585.977 us; speedup vs baseline: 3.1720x; 1.3595x over previous
//
#include <hip/hip_runtime.h>

#define N_NODES 100000
#define N_EDGES 1600000
#define FEAT 256
#define KTOT 512

typedef __attribute__((ext_vector_type(8))) short short8v;     // 8 bf16 = 4 VGPRs
typedef __attribute__((ext_vector_type(4))) float f32x4;
typedef __attribute__((ext_vector_type(4))) unsigned short ushort4v;

__device__ __forceinline__ unsigned short f2bf(float f) {
    unsigned u = __float_as_uint(f);
    return (unsigned short)((u + 0x7FFFu + ((u >> 16) & 1u)) >> 16);   // RNE
}
__device__ __forceinline__ float bf2f(unsigned short s) {
    return __uint_as_float(((unsigned)s) << 16);
}
__device__ __forceinline__ short8v zero8() {
    short8v v;
    #pragma unroll
    for (int i = 0; i < 8; ++i) v[i] = 0;
    return v;
}

// ---------------- workspace layout ----------------
// xh  : [N][512] bf16  — cols 0:256 = z (aggregated), 256:512 = bf16(h)
// Bt  : [256][512] bf16 — Bt[n][k<256]=W[k][n], Bt[n][k>=256]=res_w[n][k-256]
constexpr size_t OFF_XH     = 0;
constexpr size_t XH_BYTES   = (size_t)N_NODES * KTOT * 2;      // 102,400,000
constexpr size_t OFF_BT     = XH_BYTES;
constexpr size_t OFF_OFFS   = OFF_BT + 262144;
constexpr size_t OFF_CURSOR = OFF_OFFS + 400128;
constexpr size_t OFF_DEG    = OFF_CURSOR + 400128;
constexpr size_t OFF_BSUM   = OFF_DEG + 400128;
constexpr size_t OFF_CSR    = OFF_BSUM + 1024;
constexpr size_t WS_NEEDED  = OFF_CSR + (size_t)N_EDGES * 4;   // ~110.3 MB

// ---------------- prep kernels ----------------
__global__ __launch_bounds__(256) void cast_h_kernel(
    const float* __restrict__ h, unsigned short* __restrict__ xh)
{
    int tid = blockIdx.x * 256 + threadIdx.x;      // 3.2M threads, 8 elems each
    int row = tid >> 5;                            // 32 threads per row
    int c8  = (tid & 31) * 8;
    const float4* p = (const float4*)&h[(size_t)row * FEAT + c8];
    float4 a = p[0], b = p[1];
    unsigned short tmp[8];
    tmp[0]=f2bf(a.x); tmp[1]=f2bf(a.y); tmp[2]=f2bf(a.z); tmp[3]=f2bf(a.w);
    tmp[4]=f2bf(b.x); tmp[5]=f2bf(b.y); tmp[6]=f2bf(b.z); tmp[7]=f2bf(b.w);
    *(short8v*)&xh[(size_t)row * KTOT + 256 + c8] = *(short8v*)tmp;
}

__global__ __launch_bounds__(256) void prep_b_kernel(
    const float* __restrict__ W, const float* __restrict__ res_w,
    unsigned short* __restrict__ Bt)
{
    int n = blockIdx.x, t = threadIdx.x;
    Bt[(size_t)n * KTOT + t]       = f2bf(W[(size_t)t * FEAT + n]);       // W^T
    Bt[(size_t)n * KTOT + 256 + t] = f2bf(res_w[(size_t)n * FEAT + t]);   // res_w
}

// ---------------- CSR build ----------------
__global__ __launch_bounds__(256) void hist_kernel(
    const int* __restrict__ dst, int* __restrict__ deg)
{
    int e = blockIdx.x * 256 + threadIdx.x;
    if (e < N_EDGES) atomicAdd(&deg[dst[e]], 1);
}

// ---- three-phase device-wide exclusive scan of deg -> offs, cursor ----
#define SCAN_NPB 1024                 // nodes per block
#define SCAN_BLOCKS ((N_NODES + SCAN_NPB - 1) / SCAN_NPB)   // 98

__global__ __launch_bounds__(256) void scan_partial_kernel(
    const int* __restrict__ deg, int* __restrict__ bsum)
{
    __shared__ int sdata[256];
    const int b = blockIdx.x, t = threadIdx.x;
    const int base = b * SCAN_NPB + t * 4;
    int s = 0;
    #pragma unroll
    for (int i = 0; i < 4; ++i) {
        int n = base + i;
        if (n < N_NODES) s += deg[n];
    }
    sdata[t] = s;
    __syncthreads();
    #pragma unroll
    for (int d = 128; d > 0; d >>= 1) {
        if (t < d) sdata[t] += sdata[t + d];
        __syncthreads();
    }
    if (t == 0) bsum[b] = sdata[0];
}

__global__ __launch_bounds__(128) void scan_bsum_kernel(
    int* __restrict__ bsum, int* __restrict__ offs)
{
    __shared__ int tmp[128];
    const int t = threadIdx.x;
    int v = (t < SCAN_BLOCKS) ? bsum[t] : 0;
    tmp[t] = v;
    __syncthreads();
    for (int d = 1; d < 128; d <<= 1) {
        int u = (t >= d) ? tmp[t - d] : 0;
        __syncthreads();
        tmp[t] += u;
        __syncthreads();
    }
    if (t < SCAN_BLOCKS) bsum[t] = tmp[t] - v;   // exclusive
    if (t == 0) offs[N_NODES] = N_EDGES;          // total degree is fixed
}

__global__ __launch_bounds__(256) void scan_final_kernel(
    const int* __restrict__ deg, const int* __restrict__ bsum,
    int* __restrict__ offs, int* __restrict__ cursor)
{
    __shared__ int sdata[256];
    const int b = blockIdx.x, t = threadIdx.x;
    const int base = b * SCAN_NPB + t * 4;
    int d0[4];
    int s = 0;
    #pragma unroll
    for (int i = 0; i < 4; ++i) {
        int n = base + i;
        d0[i] = (n < N_NODES) ? deg[n] : 0;
        s += d0[i];
    }
    sdata[t] = s;
    const int own = s;
    __syncthreads();
    for (int d = 1; d < 256; d <<= 1) {           // inclusive Hillis-Steele
        int u = (t >= d) ? sdata[t - d] : 0;
        __syncthreads();
        sdata[t] += u;
        __syncthreads();
    }
    int prefix = bsum[b] + sdata[t] - own;        // exclusive within grid
    #pragma unroll
    for (int i = 0; i < 4; ++i) {
        int n = base + i;
        if (n < N_NODES) {
            offs[n]   = prefix;
            cursor[n] = prefix;
            prefix += d0[i];
        }
    }
}

__global__ __launch_bounds__(256) void fill_kernel(
    const int* __restrict__ src, const int* __restrict__ dst,
    int* __restrict__ cursor, int* __restrict__ csr_src)
{
    int e = blockIdx.x * 256 + threadIdx.x;
    if (e < N_EDGES) {
        int d = dst[e];
        int p = atomicAdd(&cursor[d], 1);
        csr_src[p] = src[e];
    }
}

// ---------------- aggregate: z[n] = norm[n] * sum_e bf16(h)[src_e]*norm[src_e] ----------------
__global__ __launch_bounds__(256) void aggregate_kernel(
    const float* __restrict__ norm,
    const int*   __restrict__ offs,
    const int*   __restrict__ csr_src,
    unsigned short* __restrict__ xh)     // reads h half (+256), writes z half
{
    const int wave = threadIdx.x >> 6;
    const int lane = threadIdx.x & 63;
    const int n    = blockIdx.x * 4 + wave;
    if (n >= N_NODES) return;
    const int start = offs[n];
    const int end   = offs[n + 1];
    float a0=0,a1=0,a2=0,a3=0, b0=0,b1=0,b2=0,b3=0;
    int e = start;
    for (; e + 1 < end; e += 2) {
        int s0 = csr_src[e];
        int s1 = csr_src[e + 1];
        float m0 = norm[s0], m1 = norm[s1];
        ushort4v v0 = *(const ushort4v*)&xh[(size_t)s0 * KTOT + 256 + lane * 4];
        ushort4v v1 = *(const ushort4v*)&xh[(size_t)s1 * KTOT + 256 + lane * 4];
        a0 = fmaf(bf2f(v0.x), m0, a0); a1 = fmaf(bf2f(v0.y), m0, a1);
        a2 = fmaf(bf2f(v0.z), m0, a2); a3 = fmaf(bf2f(v0.w), m0, a3);
        b0 = fmaf(bf2f(v1.x), m1, b0); b1 = fmaf(bf2f(v1.y), m1, b1);
        b2 = fmaf(bf2f(v1.z), m1, b2); b3 = fmaf(bf2f(v1.w), m1, b3);
    }
    if (e < end) {
        int s0 = csr_src[e];
        float m0 = norm[s0];
        ushort4v v0 = *(const ushort4v*)&xh[(size_t)s0 * KTOT + 256 + lane * 4];
        a0 = fmaf(bf2f(v0.x), m0, a0); a1 = fmaf(bf2f(v0.y), m0, a1);
        a2 = fmaf(bf2f(v0.z), m0, a2); a3 = fmaf(bf2f(v0.w), m0, a3);
    }
    float nm = norm[n];
    unsigned short tmp[4];
    tmp[0] = f2bf((a0 + b0) * nm);
    tmp[1] = f2bf((a1 + b1) * nm);
    tmp[2] = f2bf((a2 + b2) * nm);
    tmp[3] = f2bf((a3 + b3) * nm);
    *(ushort4v*)&xh[(size_t)n * KTOT + lane * 4] = *(ushort4v*)tmp;
}

// ---------------- fused MFMA GEMM: out = relu(xh @ Bt^T + bias + res_b) ----------------
// block tile 128x128, 4 waves in 2x2, wave tile 64x64 (4x4 frags of 16x16x32)
#define GBM 128
#define GBN 128
#define GBK 32
#define LDT 40   // shorts per LDS row = 80 B (16B-aligned, spreads banks)

__global__ __launch_bounds__(256) void mfma_gemm_kernel(
    const unsigned short* __restrict__ xh,   // A: [N][512] bf16
    const unsigned short* __restrict__ Bt,   // [256][512] bf16 (n-major)
    const float* __restrict__ bias,
    const float* __restrict__ res_b,
    float* __restrict__ out)
{
    __shared__ unsigned short As[GBM * LDT];
    __shared__ unsigned short Bs[GBN * LDT];
    const int t    = threadIdx.x;
    const int m0   = blockIdx.x * GBM;
    const int n0   = blockIdx.y * GBN;
    const int wave = t >> 6, lane = t & 63;
    const int wm   = wave >> 1, wn = wave & 1;
    const int lrow = lane & 15, kg = lane >> 4;   // frag row/col + k-group

    f32x4 zf = {0.f, 0.f, 0.f, 0.f};
    f32x4 acc[4][4];
    #pragma unroll
    for (int i = 0; i < 4; ++i)
        #pragma unroll
        for (int j = 0; j < 4; ++j) acc[i][j] = zf;

    for (int k0 = 0; k0 < KTOT; k0 += GBK) {
        #pragma unroll
        for (int it = 0; it < 2; ++it) {
            int idx = it * 256 + t;      // 0..511 -> 128 rows x 4 chunks(16B)
            int row = idx >> 2;
            int ch  = (idx & 3) * 8;     // shorts
            int grow = m0 + row;
            short8v va = zero8();
            if (grow < N_NODES)
                va = *(const short8v*)&xh[(size_t)grow * KTOT + k0 + ch];
            *(short8v*)&As[row * LDT + ch] = va;
            short8v vb = *(const short8v*)&Bt[(size_t)(n0 + row) * KTOT + k0 + ch];
            *(short8v*)&Bs[row * LDT + ch] = vb;
        }
        __syncthreads();

        short8v af[4], bfr[4];
        #pragma unroll
        for (int i = 0; i < 4; ++i) {
            af[i]  = *(const short8v*)&As[(wm * 64 + i * 16 + lrow) * LDT + kg * 8];
            bfr[i] = *(const short8v*)&Bs[(wn * 64 + i * 16 + lrow) * LDT + kg * 8];
        }
        #pragma unroll
        for (int i = 0; i < 4; ++i)
            #pragma unroll
            for (int j = 0; j < 4; ++j)
                acc[i][j] = __builtin_amdgcn_mfma_f32_16x16x32_bf16(
                    af[i], bfr[j], acc[i][j], 0, 0, 0);
        __syncthreads();
    }

    // D layout: col = lane&15, row = 4*(lane>>4) + reg
    #pragma unroll
    for (int j = 0; j < 4; ++j) {
        int col = n0 + wn * 64 + j * 16 + lrow;
        float bb = bias[col] + res_b[col];
        #pragma unroll
        for (int i = 0; i < 4; ++i) {
            int rbase = m0 + wm * 64 + i * 16 + kg * 4;
            #pragma unroll
            for (int r = 0; r < 4; ++r) {
                int row = rbase + r;
                if (row < N_NODES)
                    out[(size_t)row * FEAT + col] = fmaxf(acc[i][j][r] + bb, 0.f);
            }
        }
    }
}

// ================= fallback fp32 path (only if ws too small) =================
#define BM 64
#define BN 64
#define BK 64
#define LDSS 68

template<int MODE>
__global__ __launch_bounds__(256) void gemm_kernel(
    const float* __restrict__ A, const float* __restrict__ B,
    const float* __restrict__ norm, const float* __restrict__ bias,
    const float* __restrict__ res_b, const float* __restrict__ agg,
    float* __restrict__ C)
{
    __shared__ float A_T[BK][LDSS];
    __shared__ float B_s[BK][LDSS];
    const int t = threadIdx.x;
    const int m0 = blockIdx.x * BM, n0 = blockIdx.y * BN;
    const int tx = t & 15, ty = t >> 4;
    float acc[4][4] = {};
    for (int k0 = 0; k0 < FEAT; k0 += BK) {
        #pragma unroll
        for (int i = 0; i < 4; ++i) {
            int idx = i * 256 + t;
            int m = idx >> 4, k4 = (idx & 15) * 4;
            int row = m0 + m;
            float4 v = make_float4(0.f,0.f,0.f,0.f);
            if (row < N_NODES) v = *(const float4*)&A[(size_t)row * FEAT + k0 + k4];
            A_T[k4+0][m]=v.x; A_T[k4+1][m]=v.y; A_T[k4+2][m]=v.z; A_T[k4+3][m]=v.w;
        }
        #pragma unroll
        for (int i = 0; i < 4; ++i) {
            int idx = i * 256 + t;
            if (MODE == 0) {
                int k = idx >> 4, n4 = (idx & 15) * 4;
                *(float4*)&B_s[k][n4] = *(const float4*)&B[(size_t)(k0+k)*FEAT + n0 + n4];
            } else {
                int n = idx >> 4, k4 = (idx & 15) * 4;
                float4 v = *(const float4*)&B[(size_t)(n0+n)*FEAT + k0 + k4];
                B_s[k4+0][n]=v.x; B_s[k4+1][n]=v.y; B_s[k4+2][n]=v.z; B_s[k4+3][n]=v.w;
            }
        }
        __syncthreads();
        #pragma unroll
        for (int kk = 0; kk < BK; ++kk) {
            float4 av = *(const float4*)&A_T[kk][ty*4];
            float4 bv = *(const float4*)&B_s[kk][tx*4];
            const float a[4]={av.x,av.y,av.z,av.w}, b[4]={bv.x,bv.y,bv.z,bv.w};
            #pragma unroll
            for (int i=0;i<4;++i)
                #pragma unroll
                for (int j=0;j<4;++j) acc[i][j]=fmaf(a[i],b[j],acc[i][j]);
        }
        __syncthreads();
    }
    if (MODE == 0) {
        #pragma unroll
        for (int i=0;i<4;++i) {
            int row=m0+ty*4+i;
            if (row<N_NODES) {
                float nm=norm[row];
                float4 o; o.x=acc[i][0]*nm; o.y=acc[i][1]*nm; o.z=acc[i][2]*nm; o.w=acc[i][3]*nm;
                *(float4*)&C[(size_t)row*FEAT+n0+tx*4]=o;
            }
        }
    } else {
        float4 bv=*(const float4*)&bias[n0+tx*4];
        float4 rb=*(const float4*)&res_b[n0+tx*4];
        #pragma unroll
        for (int i=0;i<4;++i) {
            int row=m0+ty*4+i;
            if (row<N_NODES) {
                float nm=norm[row];
                float4 ag=*(const float4*)&agg[(size_t)row*FEAT+n0+tx*4];
                float4 o;
                o.x=fmaxf(fmaf(ag.x,nm,bv.x)+acc[i][0]+rb.x,0.f);
                o.y=fmaxf(fmaf(ag.y,nm,bv.y)+acc[i][1]+rb.y,0.f);
                o.z=fmaxf(fmaf(ag.z,nm,bv.z)+acc[i][2]+rb.z,0.f);
                o.w=fmaxf(fmaf(ag.w,nm,bv.w)+acc[i][3]+rb.w,0.f);
                *(float4*)&C[(size_t)row*FEAT+n0+tx*4]=o;
            }
        }
    }
}

__global__ __launch_bounds__(256) void scatter_kernel(
    const float* __restrict__ hw, const int* __restrict__ src,
    const int* __restrict__ dst, float* __restrict__ agg)
{
    const int t = threadIdx.x;
    const int e0 = blockIdx.x * 8;
    #pragma unroll
    for (int i = 0; i < 8; ++i) {
        int e = e0 + i;
        if (e < N_EDGES) {
            int s = src[e], d = dst[e];
            atomicAdd(&agg[(size_t)d * FEAT + t], hw[(size_t)s * FEAT + t]);
        }
    }
}

extern "C" void kernel_launch(void* const* d_in, const int* in_sizes, int n_in,
                              void* d_out, int out_size, void* d_ws, size_t ws_size,
                              hipStream_t stream) {
    const float* h      = (const float*)d_in[0];
    const float* norm   = (const float*)d_in[1];
    const int*   src    = (const int*)d_in[2];
    const int*   dst    = (const int*)d_in[3];
    const float* weight = (const float*)d_in[4];
    const float* bias   = (const float*)d_in[5];
    const float* res_w  = (const float*)d_in[6];
    const float* res_b  = (const float*)d_in[7];
    float* out = (float*)d_out;
    char* ws = (char*)d_ws;

    if (ws_size >= WS_NEEDED) {
        unsigned short* xh  = (unsigned short*)(ws + OFF_XH);
        unsigned short* Bt  = (unsigned short*)(ws + OFF_BT);
        int* offs   = (int*)(ws + OFF_OFFS);
        int* cursor = (int*)(ws + OFF_CURSOR);
        int* deg    = (int*)(ws + OFF_DEG);
        int* bsum   = (int*)(ws + OFF_BSUM);
        int* csr    = (int*)(ws + OFF_CSR);

        cast_h_kernel<<<N_NODES * FEAT / 8 / 256, 256, 0, stream>>>(h, xh);
        prep_b_kernel<<<256, 256, 0, stream>>>(weight, res_w, Bt);
        hipMemsetAsync(deg, 0, (size_t)N_NODES * 4, stream);
        hist_kernel<<<(N_EDGES + 255) / 256, 256, 0, stream>>>(dst, deg);
        scan_partial_kernel<<<SCAN_BLOCKS, 256, 0, stream>>>(deg, bsum);
        scan_bsum_kernel<<<1, 128, 0, stream>>>(bsum, offs);
        scan_final_kernel<<<SCAN_BLOCKS, 256, 0, stream>>>(deg, bsum, offs, cursor);
        fill_kernel<<<(N_EDGES + 255) / 256, 256, 0, stream>>>(src, dst, cursor, csr);
        aggregate_kernel<<<(N_NODES + 3) / 4, 256, 0, stream>>>(norm, offs, csr, xh);
        dim3 gg((N_NODES + GBM - 1) / GBM, FEAT / GBN);
        mfma_gemm_kernel<<<gg, 256, 0, stream>>>(xh, Bt, bias, res_b, out);
    } else {
        float* hw = (float*)ws;
        dim3 gdim((N_NODES + BM - 1) / BM, FEAT / BN);
        gemm_kernel<0><<<gdim, 256, 0, stream>>>(h, weight, norm, nullptr, nullptr, nullptr, hw);
        hipMemsetAsync(out, 0, (size_t)N_NODES * FEAT * sizeof(float), stream);
        scatter_kernel<<<N_EDGES / 8, 256, 0, stream>>>(hw, src, dst, out);
        gemm_kernel<1><<<gdim, 256, 0, stream>>>(h, res_w, norm, bias, res_b, out, out);
    }
}